// Round 1
// 24.932 us; speedup vs baseline: 1.1308x; 1.1308x over previous
//
#include <hip/hip_runtime.h>
#include <hip/hip_fp16.h>
#include <math.h>

#define D 64
#define NS 64      // S: tokens per shard
#define H 8
#define NSHARD 128 // B * n_shards
#define KPB 8      // k columns per block (2 per wave)
#define NBLK (NSHARD * (D / KPB))   // 1024 blocks = 4/CU exactly
#define TBL 512    // LUT entries over [-8, 8)
constexpr float LR = 0.01f;
constexpr float WD = 0.01f;
constexpr float GSCALE = (float)TBL / 16.0f;   // 32 entries per unit g
constexpr float GOFF   = 8.0f * GSCALE;        // 256
constexpr float TMAX   = (float)TBL - 2.0f + 0.99f;   // 510.99

typedef __attribute__((ext_vector_type(8))) short bf16x8;  // 8 bf16 (4 VGPR)
typedef __attribute__((ext_vector_type(4))) float f32x4;

__device__ __forceinline__ short f2bf(float f) {           // f32 -> bf16 RNE
    unsigned u = __float_as_uint(f);
    return (short)((u + 0x7FFF + ((u >> 16) & 1)) >> 16);
}

template<int CTRL, int RM>
__device__ __forceinline__ float dpp_add(float v) {
    int t = __builtin_amdgcn_update_dpp(0, __float_as_int(v), CTRL, RM, 0xf, true);
    return v + __int_as_float(t);
}

// LDS layout (39432 B -> 4 blocks/CU):
//   [0,    18432): WT[2][64][72] bf16   -- W0+Wq staging (dead after MFMA phase)
//     overlay:  [0,8704) vbuf[4][8][68] f32; [8704,10752) osh[64][8] f32;
//               [10752,14848) Tl2[512] float2 {f, df}
//   [18432,35328): XQ[64][66] u32 (half2(x,q))
//   [35328,37376): Esm[64][8] f32  (this block's 8 k-columns of E)
//   [37376,39432): Tlraw[514] f32 (raw LUT values, built pre-sync)
#define SM_BYTES 39432
#define OFF_XQ   18432
#define OFF_ESM  35328
#define OFF_TLR  37376
#define OFF_OSH  8704
#define OFF_TL2  10752

__global__ __launch_bounds__(256, 4) void tnt_fused(const float* __restrict__ X,
                                                    const float* __restrict__ mem0,
                                                    const float* __restrict__ opt,
                                                    const float* __restrict__ Wq,
                                                    float* __restrict__ out) {
    __shared__ __align__(16) char smem[SM_BYTES];
    short*    WT  = (short*)(smem);               // [2][64][72]
    unsigned* XQu = (unsigned*)(smem + OFF_XQ);   // [64][66]
    float (*Esm)[KPB] = (float(*)[KPB])(smem + OFF_ESM);
    float*    Tlr = (float*)(smem + OFF_TLR);
    float (*vb4)[8][68] = (float(*)[8][68])(smem);
    float (*osh)[KPB]   = (float(*)[KPB])(smem + OFF_OSH);
    float2*   Tl2 = (float2*)(smem + OFF_TL2);

    // XCD swizzle: the 8 blocks of a shard land on one XCD's L2 (1024 % 8 == 0)
    const int bid  = ((int)blockIdx.x & 7) * (NBLK / 8) + ((int)blockIdx.x >> 3);
    const int n    = bid >> 3;
    const int kq   = bid & 7;
    const int tid  = threadIdx.x;
    const int wv   = tid >> 6;
    const int lane = tid & 63;
    const int l15  = lane & 15, lhi = lane >> 4;
    const int k0   = (kq << 3) + (wv << 1);       // first of this wave's 2 k-cols

    const float* Xs = X + n * NS * D;

    // ---- phase 1: stage W0^T and Wq^T bf16 in one pass ----
    {
        const int m     = tid >> 7;            // matrix 0/1
        const int kcol  = tid & 63;            // output column of W
        const int gbase = ((tid >> 6) & 1) * 4;
        const float* Wm = m ? Wq : mem0;
#pragma unroll
        for (int gg = 0; gg < 4; ++gg) {
            const int g = gbase + gg;
            bf16x8 pk;
#pragma unroll
            for (int i = 0; i < 8; ++i)
                pk[i] = f2bf(Wm[(g * 8 + i) * D + kcol]);   // coalesced per i
            *(bf16x8*)(WT + (m * 64 + kcol) * 72 + g * 8) = pk;
        }
    }
    // A-frags (rows wv*16 + l15), shared by both GEMMs
    bf16x8 afrag[2];
    {
        const float* xrow = Xs + (wv * 16 + l15) * D + lhi * 8;
#pragma unroll
        for (int ks = 0; ks < 2; ++ks) {
            const float4 u0 = *(const float4*)(xrow + ks * 32);
            const float4 u1 = *(const float4*)(xrow + ks * 32 + 4);
            bf16x8 a;
            a[0]=f2bf(u0.x); a[1]=f2bf(u0.y); a[2]=f2bf(u0.z); a[3]=f2bf(u0.w);
            a[4]=f2bf(u1.x); a[5]=f2bf(u1.y); a[6]=f2bf(u1.z); a[7]=f2bf(u1.w);
            afrag[ks] = a;
        }
    }
    const float2 m0v  = *(const float2*)(mem0 + lane * D + k0);  // both k-cols
    const float wdm00 = WD * m0v.x;
    const float wdm01 = WD * m0v.y;
    __syncthreads();

    // ---- phase 2: both GEMMs; E -> Esm (8 cols); xq tile; raw LUT ----
    {
        f32x4 accE[4], accQ[4];
#pragma unroll
        for (int nt = 0; nt < 4; ++nt) { accE[nt] = 0; accQ[nt] = 0; }
#pragma unroll
        for (int nt = 0; nt < 4; ++nt) {
            const int col = nt * 16 + l15;
#pragma unroll
            for (int ks = 0; ks < 2; ++ks) {
                const bf16x8 b0 = *(const bf16x8*)(WT + col * 72 + ks * 32 + lhi * 8);
                const bf16x8 b1 = *(const bf16x8*)(WT + (64 + col) * 72 + ks * 32 + lhi * 8);
                accE[nt] = __builtin_amdgcn_mfma_f32_16x16x32_bf16(afrag[ks], b0, accE[nt], 0,0,0);
                accQ[nt] = __builtin_amdgcn_mfma_f32_16x16x32_bf16(afrag[ks], b1, accQ[nt], 0,0,0);
            }
        }
        // E epilogue: cols kq*8+j (j=0..7) -> Esm[row][j].
        // Those cols live in nt_e = kq>>1, l15 half selected by kq&1.
        const float c = (2.0f / (float)D) * GSCALE;
        if ((l15 >> 3) == (kq & 1)) {
            const int nt_e = kq >> 1;            // wave-uniform select (no scratch)
            const f32x4 aE = (nt_e == 0) ? accE[0] : (nt_e == 1) ? accE[1]
                           : (nt_e == 2) ? accE[2] : accE[3];
            const int j = l15 & 7;
#pragma unroll
            for (int r = 0; r < 4; ++r) {
                const int row = wv * 16 + lhi * 4 + r;
                const int col = (kq << 3) + j;
                Esm[row][j] = c * (aE[r] - Xs[row * D + col]);
            }
        }
        // Q epilogue: full xq tile half2(x, q)
#pragma unroll
        for (int nt = 0; nt < 4; ++nt) {
#pragma unroll
            for (int r = 0; r < 4; ++r) {
                const int row = wv * 16 + lhi * 4 + r;
                const int col = nt * 16 + l15;
                const __half2 h = __halves2half2(__float2half_rn(Xs[row * D + col]),
                                                 __float2half_rn(accQ[nt][r]));
                XQu[row * 66 + col] = *(const unsigned*)&h;
            }
        }
    }
    {   // LR-scaled raw LUT f(j), j in [0,512] (513 entries; one eval per entry)
        float w1d[H], b1d[H], w2[H];
#pragma unroll
        for (int h = 0; h < H; ++h) {
            w1d[h] = 2.0f * opt[h]; b1d[h] = 2.0f * opt[H + h]; w2[h] = opt[2 * H + h];
        }
        const float b2 = opt[3 * H];
        for (int jj = tid; jj < TBL + 1; jj += 256) {   // 2 iters (3 for tid==0)
            const float g = ((float)jj - GOFF) / GSCALE;
            float acc = b2;
#pragma unroll
            for (int h = 0; h < H; ++h) {
                const float u = __expf(fmaf(w1d[h], g, b1d[h]));   // e^{2y}
                acc = fmaf(w2[h], (u - 1.0f) * __builtin_amdgcn_rcpf(u + 1.0f), acc);
            }
            Tlr[jj] = LR * acc;
        }
    }
    __syncthreads();   // WT reads done (overlay free); Esm/XQ/Tlr ready

    // build (value, delta) pair LUT in the dead WT overlay; fetch E columns
    const float e0 = Esm[lane][(wv << 1)];       // E[n, s=lane, k0] * GSCALE
    const float e1 = Esm[lane][(wv << 1) + 1];   // E[n, s=lane, k0+1] * GSCALE
#pragma unroll
    for (int j = tid; j < TBL; j += 256) {       // 2 iterations
        const float a = Tlr[j];
        Tl2[j] = make_float2(a, Tlr[j + 1] - a);
    }
    __syncthreads();   // Tl2 ready

    // ---- main loop: 8 batches of 8 steps, 2 k-columns interleaved ----
    float (*vb)[68] = vb4[wv];
    float cum0 = m0v.x;
    float cum1 = m0v.y;

    const int sp = lane >> 3;
    const int jr = lane & 7;

#pragma unroll 1
    for (int b = 0; b < 8; ++b) {
        float q8[8], v0[8], v1[8];
#pragma unroll
        for (int u = 0; u < 8; ++u) {          // independent across u AND k: full ILP
            const int s = (b << 3) + u;
            const float ek0 = __int_as_float(
                __builtin_amdgcn_readlane(__float_as_int(e0), s));
            const float ek1 = __int_as_float(
                __builtin_amdgcn_readlane(__float_as_int(e1), s));
            const unsigned w = XQu[s * 66 + lane];
            const __half2 hv = *(const __half2*)&w;
            const float xv = __low2float(hv);
            q8[u] = __high2float(hv);
            float t0 = __builtin_amdgcn_fmed3f(fmaf(xv, ek0, GOFF), 0.0f, TMAX);
            float t1 = __builtin_amdgcn_fmed3f(fmaf(xv, ek1, GOFF), 0.0f, TMAX);
            const int   i0 = (int)t0;
            const int   i1 = (int)t1;
            const float fr0 = t0 - (float)i0;
            const float fr1 = t1 - (float)i1;
            const float2 L0 = Tl2[i0];          // single b64 gather per (u,k)
            const float2 L1 = Tl2[i1];
            v0[u] = fmaf(fr0, L0.y, L0.x) + wdm00;
            v1[u] = fmaf(fr1, L1.y, L1.x) + wdm01;
        }
        float p1[8];
#pragma unroll
        for (int u = 0; u < 8; ++u) {          // two interleaved serial chains
            cum0 -= v0[u];
            cum1 -= v1[u];
            vb[u][lane] = q8[u] * cum0;
            p1[u] = q8[u] * cum1;
        }
        // reduce k0: lane = sp*8 + jr sums vb[sp][jr*8..jr*8+7]
        {
            const float* row = &vb[sp][0];
            const float4 a  = *(const float4*)(row + (jr << 3) + 0);
            const float4 c2 = *(const float4*)(row + (jr << 3) + 4);
            float ssum = ((a.x + a.y) + (a.z + a.w)) + ((c2.x + c2.y) + (c2.z + c2.w));
            ssum = dpp_add<0xB1, 0xf>(ssum);   // quad_perm xor 1
            ssum = dpp_add<0x4E, 0xf>(ssum);   // quad_perm xor 2
            ssum = dpp_add<0x114, 0xf>(ssum);  // row_shr:4 (lanes jr==4 hold 8-sum)
            if ((lane & 7) == 4) osh[(b << 3) + sp][(wv << 1)] = ssum;
        }
        __builtin_amdgcn_wave_barrier();       // keep WAR order: reads above, writes below
#pragma unroll
        for (int u = 0; u < 8; ++u)
            vb[u][lane] = p1[u];
        // reduce k1
        {
            const float* row = &vb[sp][0];
            const float4 a  = *(const float4*)(row + (jr << 3) + 0);
            const float4 c2 = *(const float4*)(row + (jr << 3) + 4);
            float ssum = ((a.x + a.y) + (a.z + a.w)) + ((c2.x + c2.y) + (c2.z + c2.w));
            ssum = dpp_add<0xB1, 0xf>(ssum);
            ssum = dpp_add<0x4E, 0xf>(ssum);
            ssum = dpp_add<0x114, 0xf>(ssum);
            if ((lane & 7) == 4) osh[(b << 3) + sp][(wv << 1) + 1] = ssum;
        }
    }

    __syncthreads();
    // out: this block's 8 columns for all 64 s; 2 floats per thread (b64 store)
    const int s_ = tid >> 2;
    const int c2 = (tid & 3) << 1;
    const float2 o = *(const float2*)&osh[s_][c2];
    *(float2*)(out + (n * NS + s_) * D + (kq << 3) + c2) = o;
}

extern "C" void kernel_launch(void* const* d_in, const int* in_sizes, int n_in,
                              void* d_out, int out_size, void* d_ws, size_t ws_size,
                              hipStream_t stream) {
    const float* X    = (const float*)d_in[0];   // (4,2048,64)
    const float* mem0 = (const float*)d_in[1];   // (4096,)
    const float* opt  = (const float*)d_in[2];   // (25,)
    const float* Wq   = (const float*)d_in[3];   // (64,64)
    float* out = (float*)d_out;

    tnt_fused<<<dim3(NBLK), dim3(256), 0, stream>>>(X, mem0, opt, Wq, out);
}

// Round 2
// 24.098 us; speedup vs baseline: 1.1699x; 1.0346x over previous
//
#include <hip/hip_runtime.h>
#include <hip/hip_fp16.h>
#include <math.h>

#define D 64
#define NS 64      // S: tokens per shard
#define H 8
#define NSHARD 128 // B * n_shards
#define KPB 8      // k columns per block (2 per wave)
#define NBLK (NSHARD * (D / KPB))   // 1024 blocks = 4/CU exactly
#define TBL 512    // LUT entries over [-8, 8), nearest-neighbor (centers baked)
constexpr float LR = 0.01f;
constexpr float WD = 0.01f;
constexpr float GSCALE = (float)TBL / 16.0f;   // 32 entries per unit g
constexpr float GOFF   = 8.0f * GSCALE;        // 256
constexpr float TMAXN  = 511.0f;               // clamp for nearest index

typedef __attribute__((ext_vector_type(8))) short bf16x8;  // 8 bf16 (4 VGPR)
typedef __attribute__((ext_vector_type(4))) float f32x4;

__device__ __forceinline__ short f2bf(float f) {           // f32 -> bf16 RNE
    unsigned u = __float_as_uint(f);
    return (short)((u + 0x7FFF + ((u >> 16) & 1)) >> 16);
}

template<int CTRL, int RM>
__device__ __forceinline__ float dpp_add(float v) {
    int t = __builtin_amdgcn_update_dpp(0, __float_as_int(v), CTRL, RM, 0xf, true);
    return v + __int_as_float(t);
}

// LDS layout (39936 B -> 4 blocks/CU):
//   [0,    18432): WT[2][64][72] bf16   -- W0+Wq staging (dead after MFMA phase)
//     overlay:  [0,4096) P2[4 waves][8 s][16 quads] float2 ; [4096,6144) osh[64][8] f32
//   [18432,35840): XQT[64 j][68 s] u32  (half2(x,q), TRANSPOSED: row=j, col=s)
//   [35840,37888): Esm[64][8] f32  (this block's 8 k-columns of E)
//   [37888,39936): Tl[512] f32 (nearest LUT, cell centers)
#define SM_BYTES 39936
#define OFF_XQT  18432
#define OFF_ESM  35840
#define OFF_TL   37888
#define OFF_OSH  4096

__global__ __launch_bounds__(256, 4) void tnt_fused(const float* __restrict__ X,
                                                    const float* __restrict__ mem0,
                                                    const float* __restrict__ opt,
                                                    const float* __restrict__ Wq,
                                                    float* __restrict__ out) {
    __shared__ __align__(16) char smem[SM_BYTES];
    short*    WT  = (short*)(smem);               // [2][64][72]
    unsigned* XQT = (unsigned*)(smem + OFF_XQT);  // [64][68]
    float (*Esm)[KPB] = (float(*)[KPB])(smem + OFF_ESM);
    float*    Tl  = (float*)(smem + OFF_TL);
    float (*osh)[KPB] = (float(*)[KPB])(smem + OFF_OSH);

    // XCD swizzle: the 8 blocks of a shard land on one XCD's L2 (1024 % 8 == 0)
    const int bid  = ((int)blockIdx.x & 7) * (NBLK / 8) + ((int)blockIdx.x >> 3);
    const int n    = bid >> 3;
    const int kq   = bid & 7;
    const int tid  = threadIdx.x;
    const int wv   = tid >> 6;
    const int lane = tid & 63;
    const int l15  = lane & 15, lhi = lane >> 4;
    const int k0   = (kq << 3) + (wv << 1);       // first of this wave's 2 k-cols

    float2* P2w = (float2*)(smem + (wv << 10));   // per-wave quad-partial buffer

    const float* Xs = X + n * NS * D;

    // ---- phase 1: stage W0^T and Wq^T bf16 in one pass ----
    {
        const int m     = tid >> 7;            // matrix 0/1
        const int kcol  = tid & 63;            // output column of W
        const int gbase = ((tid >> 6) & 1) * 4;
        const float* Wm = m ? Wq : mem0;
#pragma unroll
        for (int gg = 0; gg < 4; ++gg) {
            const int g = gbase + gg;
            bf16x8 pk;
#pragma unroll
            for (int i = 0; i < 8; ++i)
                pk[i] = f2bf(Wm[(g * 8 + i) * D + kcol]);   // coalesced per i
            *(bf16x8*)(WT + (m * 64 + kcol) * 72 + g * 8) = pk;
        }
    }
    // A-frags (rows wv*16 + l15), shared by both GEMMs
    bf16x8 afrag[2];
    {
        const float* xrow = Xs + (wv * 16 + l15) * D + lhi * 8;
#pragma unroll
        for (int ks = 0; ks < 2; ++ks) {
            const float4 u0 = *(const float4*)(xrow + ks * 32);
            const float4 u1 = *(const float4*)(xrow + ks * 32 + 4);
            bf16x8 a;
            a[0]=f2bf(u0.x); a[1]=f2bf(u0.y); a[2]=f2bf(u0.z); a[3]=f2bf(u0.w);
            a[4]=f2bf(u1.x); a[5]=f2bf(u1.y); a[6]=f2bf(u1.z); a[7]=f2bf(u1.w);
            afrag[ks] = a;
        }
    }
    const float2 m0v  = *(const float2*)(mem0 + lane * D + k0);  // both k-cols
    const float wdm00 = WD * m0v.x;
    const float wdm01 = WD * m0v.y;
    __syncthreads();

    // ---- phase 2: both GEMMs; E -> Esm (8 cols); xq tile (transposed); LUT ----
    {
        f32x4 accE[4], accQ[4];
#pragma unroll
        for (int nt = 0; nt < 4; ++nt) { accE[nt] = 0; accQ[nt] = 0; }
#pragma unroll
        for (int nt = 0; nt < 4; ++nt) {
            const int col = nt * 16 + l15;
#pragma unroll
            for (int ks = 0; ks < 2; ++ks) {
                const bf16x8 b0 = *(const bf16x8*)(WT + col * 72 + ks * 32 + lhi * 8);
                const bf16x8 b1 = *(const bf16x8*)(WT + (64 + col) * 72 + ks * 32 + lhi * 8);
                accE[nt] = __builtin_amdgcn_mfma_f32_16x16x32_bf16(afrag[ks], b0, accE[nt], 0,0,0);
                accQ[nt] = __builtin_amdgcn_mfma_f32_16x16x32_bf16(afrag[ks], b1, accQ[nt], 0,0,0);
            }
        }
        // E epilogue: cols kq*8+j (j=0..7) -> Esm[row][j].
        const float c = (2.0f / (float)D) * GSCALE;
        if ((l15 >> 3) == (kq & 1)) {
            const int nt_e = kq >> 1;            // wave-uniform select (no scratch)
            const f32x4 aE = (nt_e == 0) ? accE[0] : (nt_e == 1) ? accE[1]
                           : (nt_e == 2) ? accE[2] : accE[3];
            const int j = l15 & 7;
#pragma unroll
            for (int r = 0; r < 4; ++r) {
                const int row = wv * 16 + lhi * 4 + r;
                const int col = (kq << 3) + j;
                Esm[row][j] = c * (aE[r] - Xs[row * D + col]);
            }
        }
        // Q epilogue: xq tile half2(x, q), stored TRANSPOSED: XQT[j][s]
#pragma unroll
        for (int nt = 0; nt < 4; ++nt) {
#pragma unroll
            for (int r = 0; r < 4; ++r) {
                const int row = wv * 16 + lhi * 4 + r;      // s
                const int col = nt * 16 + l15;              // j
                const __half2 h = __halves2half2(__float2half_rn(Xs[row * D + col]),
                                                 __float2half_rn(accQ[nt][r]));
                XQT[col * 68 + row] = *(const unsigned*)&h;
            }
        }
    }
    {   // LR-scaled nearest LUT: entry j = f at cell center g=(j+0.5-256)/32
        float w1d[H], b1d[H], w2[H];
#pragma unroll
        for (int h = 0; h < H; ++h) {
            w1d[h] = 2.0f * opt[h]; b1d[h] = 2.0f * opt[H + h]; w2[h] = opt[2 * H + h];
        }
        const float b2 = opt[3 * H];
#pragma unroll
        for (int jj = tid; jj < TBL; jj += 256) {      // 2 iterations
            const float g = ((float)jj + 0.5f - GOFF) / GSCALE;
            float acc = b2;
#pragma unroll
            for (int h = 0; h < H; ++h) {
                const float u = __expf(fmaf(w1d[h], g, b1d[h]));   // e^{2y}
                acc = fmaf(w2[h], (u - 1.0f) * __builtin_amdgcn_rcpf(u + 1.0f), acc);
            }
            Tl[jj] = LR * acc;
        }
    }
    __syncthreads();   // WT reads done (overlay free); Esm/XQT/Tl ready

    const float2 ee = *(const float2*)&Esm[lane][wv << 1];
    const float e0 = ee.x;     // E[n, s=lane, k0]   * GSCALE
    const float e1 = ee.y;     // E[n, s=lane, k0+1] * GSCALE

    // ---- main loop: 8 batches of 8 steps, 2 k-columns, DPP reduction ----
    const unsigned* xrow = XQT + lane * 68;    // this lane's j-column, along s
    uint4 xa = *(const uint4*)(xrow + 0);
    uint4 xb = *(const uint4*)(xrow + 4);
    float cum0 = m0v.x;
    float cum1 = m0v.y;
    const int g8 = lane >> 3;
    const int h8 = lane & 7;

#pragma unroll 1
    for (int b = 0; b < 8; ++b) {
        const unsigned xw[8] = {xa.x, xa.y, xa.z, xa.w, xb.x, xb.y, xb.z, xb.w};
        float q8[8], v0[8], v1[8];
#pragma unroll
        for (int u = 0; u < 8; ++u) {          // independent across u AND k
            const int s = (b << 3) + u;
            const float ek0 = __int_as_float(
                __builtin_amdgcn_readlane(__float_as_int(e0), s));
            const float ek1 = __int_as_float(
                __builtin_amdgcn_readlane(__float_as_int(e1), s));
            const __half2 hv = *(const __half2*)&xw[u];
            const float xv = __low2float(hv);
            q8[u] = __high2float(hv);
            const float t0 = __builtin_amdgcn_fmed3f(fmaf(xv, ek0, GOFF), 0.0f, TMAXN);
            const float t1 = __builtin_amdgcn_fmed3f(fmaf(xv, ek1, GOFF), 0.0f, TMAXN);
            v0[u] = Tl[(int)t0] + wdm00;       // single b32 gather per (u,k)
            v1[u] = Tl[(int)t1] + wdm01;
        }
        if (b < 7) {                           // prefetch next batch's x/q
            xa = *(const uint4*)(xrow + (b + 1) * 8);
            xb = *(const uint4*)(xrow + (b + 1) * 8 + 4);
        }
        float p1r[8];
#pragma unroll
        for (int u = 0; u < 8; ++u) {          // two interleaved serial chains
            cum0 -= v0[u];
            cum1 -= v1[u];
            v0[u]  = q8[u] * cum0;             // reuse as p0
            p1r[u] = q8[u] * cum1;
        }
        // quad partial sums (lanes of each quad -> uniform quad sum)
        float a0[8], a1[8];
#pragma unroll
        for (int u = 0; u < 8; ++u) {
            float x0 = dpp_add<0xB1, 0xf>(v0[u]);   // xor 1
            x0       = dpp_add<0x4E, 0xf>(x0);      // xor 2
            float x1 = dpp_add<0xB1, 0xf>(p1r[u]);
            x1       = dpp_add<0x4E, 0xf>(x1);
            a0[u] = x0; a1[u] = x1;
        }
        if ((lane & 3) == 0) {                 // 16 quads -> compact b64 rows
            const int q = lane >> 2;
#pragma unroll
            for (int u = 0; u < 8; ++u)
                P2w[u * 16 + q] = make_float2(a0[u], a1[u]);
        }
        __builtin_amdgcn_wave_barrier();
        // readback: lane (g8,h8) takes s=g8, quads 2*h8 and 2*h8+1 (conflict-free b128)
        const float4 pp = *(const float4*)&P2w[g8 * 16 + h8 * 2];
        float s0 = pp.x + pp.z;
        float s1 = pp.y + pp.w;
        s0 = dpp_add<0xB1, 0xf>(s0); s0 = dpp_add<0x4E, 0xf>(s0); s0 = dpp_add<0x141, 0xf>(s0);
        s1 = dpp_add<0xB1, 0xf>(s1); s1 = dpp_add<0x4E, 0xf>(s1); s1 = dpp_add<0x141, 0xf>(s1);
        if (h8 == 0)
            *(float2*)&osh[(b << 3) + g8][wv << 1] = make_float2(s0, s1);
        __builtin_amdgcn_wave_barrier();       // order readback reads vs next-batch P2 writes
    }

    __syncthreads();
    // out: this block's 8 columns for all 64 s; 2 floats per thread (b64 store)
    const int s_ = tid >> 2;
    const int c2 = (tid & 3) << 1;
    const float2 o = *(const float2*)&osh[s_][c2];
    *(float2*)(out + (n * NS + s_) * D + (kq << 3) + c2) = o;
}

extern "C" void kernel_launch(void* const* d_in, const int* in_sizes, int n_in,
                              void* d_out, int out_size, void* d_ws, size_t ws_size,
                              hipStream_t stream) {
    const float* X    = (const float*)d_in[0];   // (4,2048,64)
    const float* mem0 = (const float*)d_in[1];   // (4096,)
    const float* opt  = (const float*)d_in[2];   // (25,)
    const float* Wq   = (const float*)d_in[3];   // (64,64)
    float* out = (float*)d_out;

    tnt_fused<<<dim3(NBLK), dim3(256), 0, stream>>>(X, mem0, opt, Wq, out);
}